// Round 9
// baseline (677.576 us; speedup 1.0000x reference)
//
#include <hip/hip_runtime.h>
#include <hip/hip_bf16.h>

#define H 256
#define NTHREADS 256

// ---------- helpers ----------
static __device__ __forceinline__ float bf2f(unsigned short u) {
    return __uint_as_float(((unsigned int)u) << 16);
}
static __device__ __forceinline__ unsigned short f2bf(float f) {
    unsigned int x = __float_as_uint(f);
    unsigned int r = (x + 0x7fffu + ((x >> 16) & 1u)) >> 16;
    return (unsigned short)r;
}

typedef unsigned short us8 __attribute__((ext_vector_type(8)));
typedef __bf16 bf16x8 __attribute__((ext_vector_type(8)));
typedef float f32x4 __attribute__((ext_vector_type(4)));

// ---------- cast x (f32 -> bf16) into right half of Acat[m][512] ----------
__global__ __launch_bounds__(NTHREADS) void cast_x_kernel(
    const float* __restrict__ x, unsigned short* __restrict__ A, int n4)
{
    int i = blockIdx.x * NTHREADS + threadIdx.x;
    if (i < n4) {
        float4 v = ((const float4*)x)[i];
        ushort4 o;
        o.x = f2bf(v.x); o.y = f2bf(v.y); o.z = f2bf(v.z); o.w = f2bf(v.w);
        int m = i >> 6;          // 64 float4 per 256-col row
        int c = i & 63;
        ((ushort4*)(A + (size_t)m * 512 + H))[c] = o;
    }
}

// ---------- build Bcat[l][n][k] for all 3 layers in one launch ----------
// n in [0,256), k in [0,512): k<256 -> Wl[n][k], else Wr[n][k-256]
__global__ __launch_bounds__(NTHREADS) void cast_w_kernel(
    const float* __restrict__ Wl1, const float* __restrict__ Wr1,
    const float* __restrict__ Wl2, const float* __restrict__ Wr2,
    const float* __restrict__ Wl3, const float* __restrict__ Wr3,
    unsigned short* __restrict__ Bcat)
{
    int i = blockIdx.x * NTHREADS + threadIdx.x;   // 3*256*512 elements
    int l = i >> 17;
    int r = i & 131071;
    int n = r >> 9;
    int k = r & 511;
    const float* Wl = (l == 0) ? Wl1 : (l == 1) ? Wl2 : Wl3;
    const float* Wr = (l == 0) ? Wr1 : (l == 1) ? Wr2 : Wr3;
    float v = (k < H) ? Wl[n * H + k] : Wr[n * H + (k - H)];
    Bcat[i] = f2bf(v);
}

// ---------- degree histogram ----------
__global__ __launch_bounds__(NTHREADS) void hist_kernel(
    const int* __restrict__ dst, int* __restrict__ cnt, int E)
{
    int i = blockIdx.x * NTHREADS + threadIdx.x;
    if (i < E) atomicAdd(&cnt[dst[i]], 1);
}

// ---------- multi-block exclusive scan, stage 1 ----------
__global__ __launch_bounds__(NTHREADS) void scan_partial_kernel(
    const int* __restrict__ cnt, int* __restrict__ row_ptr,
    int* __restrict__ blocksum, int n_nodes)
{
    __shared__ int tmp[NTHREADS];
    int t = threadIdx.x;
    int i = blockIdx.x * NTHREADS + t;
    int v = (i < n_nodes) ? cnt[i] : 0;
    tmp[t] = v;
    __syncthreads();
#pragma unroll
    for (int d = 1; d < NTHREADS; d <<= 1) {
        int add = (t >= d) ? tmp[t - d] : 0;
        __syncthreads();
        tmp[t] += add;
        __syncthreads();
    }
    if (i < n_nodes) row_ptr[i] = tmp[t] - v;   // exclusive
    if (t == NTHREADS - 1) blocksum[blockIdx.x] = tmp[t];
}

// ---------- stage 2 ----------
__global__ __launch_bounds__(NTHREADS) void scan_sums_kernel(
    int* __restrict__ blocksum, int* __restrict__ blockoff,
    int* __restrict__ row_ptr, int n_blocks, int n_nodes)
{
    __shared__ int tmp[NTHREADS];
    int t = threadIdx.x;
    int v = (t < n_blocks) ? blocksum[t] : 0;
    tmp[t] = v;
    __syncthreads();
#pragma unroll
    for (int d = 1; d < NTHREADS; d <<= 1) {
        int add = (t >= d) ? tmp[t - d] : 0;
        __syncthreads();
        tmp[t] += add;
        __syncthreads();
    }
    if (t < n_blocks) blockoff[t] = tmp[t] - v;
    if (t == NTHREADS - 1) row_ptr[n_nodes] = tmp[t];
}

// ---------- stage 3 ----------
__global__ __launch_bounds__(NTHREADS) void scan_finish_kernel(
    const int* __restrict__ cnt, int* __restrict__ row_ptr,
    int* __restrict__ cursor, float* __restrict__ deg_inv,
    const int* __restrict__ blockoff, int n_nodes)
{
    int i = blockIdx.x * NTHREADS + threadIdx.x;
    if (i < n_nodes) {
        int r = row_ptr[i] + blockoff[blockIdx.x];
        row_ptr[i] = r;
        cursor[i] = r;
        deg_inv[i] = 1.0f / (float)max(cnt[i], 1);
    }
}

// ---------- bucket cursors: bucket b (dst>>6) starts at row_ptr[b*64] ----------
__global__ __launch_bounds__(NTHREADS) void bin_init_kernel(
    const int* __restrict__ row_ptr, int* __restrict__ bcursor, int nb, int n_nodes)
{
    int b = blockIdx.x * NTHREADS + threadIdx.x;
    if (b < nb) bcursor[b] = row_ptr[min(b << 6, n_nodes)];
}

// ---------- pass B: append (src,dst) into bucket regions (dense-ish 8B writes) ----------
// Replaces the old one-shot random scatter (WRITE_SIZE 51.5MB for a 3.2MB output:
// each random 4B store cost a 64B line eviction). Bucket regions are CSR segments
// [row_ptr[b*64], row_ptr[b*64+64]) so no extra histogram/scan is needed.
__global__ __launch_bounds__(NTHREADS) void bin_fill_kernel(
    const int* __restrict__ src, const int* __restrict__ dst,
    int* __restrict__ bcursor, int2* __restrict__ tmp, int E)
{
    int i = blockIdx.x * NTHREADS + threadIdx.x;
    if (i < E) {
        int d = dst[i];
        int p = atomicAdd(&bcursor[d >> 6], 1);
        tmp[p] = make_int2(src[i], d);
    }
}

// ---------- pass C: per-bucket re-scatter into final CSR ----------
// One block per bucket: all csr_src writes land in one ~4KB window owned by a single
// block (= single XCD L2), so lines accumulate all their writes before one eviction.
__global__ __launch_bounds__(NTHREADS) void csr_fill_kernel(
    const int2* __restrict__ tmp, const int* __restrict__ row_ptr,
    int* __restrict__ cursor, int* __restrict__ csr_src, int n_nodes)
{
    int b = blockIdx.x;
    int nlo = b << 6;
    int nhi = min(nlo + 64, n_nodes);
    int lo = row_ptr[nlo];
    int hi = row_ptr[nhi];
    for (int i = lo + threadIdx.x; i < hi; i += NTHREADS) {
        int2 e = tmp[i];
        int p = atomicAdd(&cursor[e.y], 1);
        csr_src[p] = e.x;
    }
}

// ---------- mean-aggregate: gather h rows (right half of Acat) -> agg (left half) ----------
// One wave per node. Lanes 0-31 even edges, 32-63 odd edges; 8 feats (16B) per lane.
__global__ __launch_bounds__(NTHREADS) void agg_kernel(
    const unsigned short* __restrict__ hsrc,   // Acat + 256 (h base), row stride 512
    unsigned short* __restrict__ aggdst,       // Acat (agg base), row stride 512
    const int* __restrict__ row_ptr, const int* __restrict__ csr_src,
    const float* __restrict__ deg_inv, int n_nodes)
{
    int wave = threadIdx.x >> 6;
    int lane = threadIdx.x & 63;
    int node = blockIdx.x * 4 + wave;
    if (node >= n_nodes) return;
    int beg = row_ptr[node];
    int cnt = row_ptr[node + 1] - beg;
    const int half = lane >> 5;
    const int foff = (lane & 31) * 8;
    const unsigned short* hb = hsrc + foff;

    float a[8] = {0.f, 0.f, 0.f, 0.f, 0.f, 0.f, 0.f, 0.f};

    for (int e = 0; e < cnt; e += 64) {
        int rem = min(64, cnt - e);
        int idx = (lane < rem) ? csr_src[beg + e + lane] : 0;
        int j = 0;
        for (; j + 16 <= rem; j += 16) {
            int s0 = __shfl(idx, j + 0 + half);
            int s1 = __shfl(idx, j + 2 + half);
            int s2 = __shfl(idx, j + 4 + half);
            int s3 = __shfl(idx, j + 6 + half);
            int s4 = __shfl(idx, j + 8 + half);
            int s5 = __shfl(idx, j + 10 + half);
            int s6 = __shfl(idx, j + 12 + half);
            int s7 = __shfl(idx, j + 14 + half);
            us8 v0 = *(const us8*)(hb + ((size_t)s0 << 9));
            us8 v1 = *(const us8*)(hb + ((size_t)s1 << 9));
            us8 v2 = *(const us8*)(hb + ((size_t)s2 << 9));
            us8 v3 = *(const us8*)(hb + ((size_t)s3 << 9));
            us8 v4 = *(const us8*)(hb + ((size_t)s4 << 9));
            us8 v5 = *(const us8*)(hb + ((size_t)s5 << 9));
            us8 v6 = *(const us8*)(hb + ((size_t)s6 << 9));
            us8 v7 = *(const us8*)(hb + ((size_t)s7 << 9));
#pragma unroll
            for (int t = 0; t < 8; ++t) a[t] += bf2f(v0[t]);
#pragma unroll
            for (int t = 0; t < 8; ++t) a[t] += bf2f(v1[t]);
#pragma unroll
            for (int t = 0; t < 8; ++t) a[t] += bf2f(v2[t]);
#pragma unroll
            for (int t = 0; t < 8; ++t) a[t] += bf2f(v3[t]);
#pragma unroll
            for (int t = 0; t < 8; ++t) a[t] += bf2f(v4[t]);
#pragma unroll
            for (int t = 0; t < 8; ++t) a[t] += bf2f(v5[t]);
#pragma unroll
            for (int t = 0; t < 8; ++t) a[t] += bf2f(v6[t]);
#pragma unroll
            for (int t = 0; t < 8; ++t) a[t] += bf2f(v7[t]);
        }
        for (; j + 8 <= rem; j += 8) {
            int s0 = __shfl(idx, j + 0 + half);
            int s1 = __shfl(idx, j + 2 + half);
            int s2 = __shfl(idx, j + 4 + half);
            int s3 = __shfl(idx, j + 6 + half);
            us8 v0 = *(const us8*)(hb + ((size_t)s0 << 9));
            us8 v1 = *(const us8*)(hb + ((size_t)s1 << 9));
            us8 v2 = *(const us8*)(hb + ((size_t)s2 << 9));
            us8 v3 = *(const us8*)(hb + ((size_t)s3 << 9));
#pragma unroll
            for (int t = 0; t < 8; ++t) a[t] += bf2f(v0[t]);
#pragma unroll
            for (int t = 0; t < 8; ++t) a[t] += bf2f(v1[t]);
#pragma unroll
            for (int t = 0; t < 8; ++t) a[t] += bf2f(v2[t]);
#pragma unroll
            for (int t = 0; t < 8; ++t) a[t] += bf2f(v3[t]);
        }
        for (; j < rem; j += 2) {
            int jj = j + half;
            int s = __shfl(idx, (jj < rem) ? jj : j);
            if (jj < rem) {
                us8 v = *(const us8*)(hb + ((size_t)s << 9));
#pragma unroll
                for (int t = 0; t < 8; ++t) a[t] += bf2f(v[t]);
            }
        }
    }

#pragma unroll
    for (int t = 0; t < 8; ++t) a[t] += __shfl_xor(a[t], 32);

    if (half == 0) {
        float di = deg_inv[node];
        us8 o;
#pragma unroll
        for (int t = 0; t < 8; ++t) o[t] = f2bf(a[t] * di);
        *(us8*)(aggdst + (size_t)node * 512 + foff) = o;
    }
}

// ---------- fused GEMM: out = ELU( Acat(M x 512) @ Bcat^T (256 x 512) + bias ) ----------
// Triple-buffered LDS (BK=32, 3x16KB=48KB -> 3 blocks/CU), COUNTED vmcnt + raw s_barrier:
// prefetch loads for tile t+1/t+2 stay in flight across the barrier. (Round-8 win: this
// broke the invariant ~61us __syncthreads-drain stall; gemm left top-5.)
__global__ __launch_bounds__(NTHREADS, 3) void gemm_kernel(
    const unsigned short* __restrict__ Acat, const unsigned short* __restrict__ Bcat,
    const float* __restrict__ bias,
    unsigned short* __restrict__ outb, float* __restrict__ outf, int M)
{
    __shared__ __align__(16) unsigned short As[3][4096];   // [buf][128 rows x 32 cols]
    __shared__ __align__(16) unsigned short Bs[3][4096];
    const int tid = threadIdx.x;
    const int lane = tid & 63;
    const int wave = tid >> 6;
    const int m0 = blockIdx.x * 128;
    const int j0 = blockIdx.y * 128;      // 2 n-tiles over N=256

    const int wy = wave >> 1;
    const int wx = wave & 1;
    const int lrow = lane & 15;
    const int kc = lane >> 4;             // 0..3 -> 16B chunk within 32-col tile row

    const int s0 = wave * 64 + lane;
    const int s1 = 256 + s0;
    const int rA0 = s0 >> 2, cA0 = (s0 & 3) ^ ((s0 >> 3) & 3);
    const int rA1 = s1 >> 2, cA1 = (s1 & 3) ^ ((s1 >> 3) & 3);
    const unsigned short* gA0 = Acat + (size_t)(m0 + rA0) * 512 + cA0 * 8;
    const unsigned short* gA1 = Acat + (size_t)(m0 + rA1) * 512 + cA1 * 8;
    const unsigned short* gB0 = Bcat + (size_t)(j0 + rA0) * 512 + cA0 * 8;
    const unsigned short* gB1 = Bcat + (size_t)(j0 + rA1) * 512 + cA1 * 8;
    const int ldsoff0 = (wave * 64) * 8;
    const int ldsoff1 = (256 + wave * 64) * 8;

    int offA[4], offB[4];
#pragma unroll
    for (int i = 0; i < 4; ++i) {
        int ra = wy * 64 + i * 16 + lrow;
        offA[i] = ra * 32 + ((kc ^ ((ra >> 1) & 3)) << 3);
        int rb = wx * 64 + i * 16 + lrow;
        offB[i] = rb * 32 + ((kc ^ ((rb >> 1) & 3)) << 3);
    }

#define STAGE(tt, buf) do {                                                         \
    const int k0_ = (tt) * 32;                                                      \
    __builtin_amdgcn_global_load_lds(                                               \
        (const __attribute__((address_space(1))) void*)(gA0 + k0_),                 \
        (__attribute__((address_space(3))) void*)(&As[buf][ldsoff0]), 16, 0, 0);    \
    __builtin_amdgcn_global_load_lds(                                               \
        (const __attribute__((address_space(1))) void*)(gA1 + k0_),                 \
        (__attribute__((address_space(3))) void*)(&As[buf][ldsoff1]), 16, 0, 0);    \
    __builtin_amdgcn_global_load_lds(                                               \
        (const __attribute__((address_space(1))) void*)(gB0 + k0_),                 \
        (__attribute__((address_space(3))) void*)(&Bs[buf][ldsoff0]), 16, 0, 0);    \
    __builtin_amdgcn_global_load_lds(                                               \
        (const __attribute__((address_space(1))) void*)(gB1 + k0_),                 \
        (__attribute__((address_space(3))) void*)(&Bs[buf][ldsoff1]), 16, 0, 0);    \
} while (0)

    f32x4 acc[4][4] = {};
    STAGE(0, 0);
    STAGE(1, 1);

    int cur = 0, stg = 2;
    for (int t = 0; t < 16; ++t) {
        if (t < 15) asm volatile("s_waitcnt vmcnt(4)" ::: "memory");
        else        asm volatile("s_waitcnt vmcnt(0)" ::: "memory");
        __builtin_amdgcn_s_barrier();
        const unsigned short* as = As[cur];
        const unsigned short* bs = Bs[cur];
        bf16x8 a[4], b[4];
#pragma unroll
        for (int i = 0; i < 4; ++i) a[i] = *(const bf16x8*)(as + offA[i]);
#pragma unroll
        for (int i = 0; i < 4; ++i) b[i] = *(const bf16x8*)(bs + offB[i]);
        if (t + 2 < 16) STAGE(t + 2, stg);
        __builtin_amdgcn_sched_barrier(0);
        __builtin_amdgcn_s_setprio(1);
#pragma unroll
        for (int i = 0; i < 4; ++i)
#pragma unroll
            for (int j = 0; j < 4; ++j)
                acc[i][j] = __builtin_amdgcn_mfma_f32_16x16x32_bf16(
                    a[i], b[j], acc[i][j], 0, 0, 0);
        __builtin_amdgcn_s_setprio(0);
        cur = (cur == 2) ? 0 : cur + 1;
        stg = (stg == 2) ? 0 : stg + 1;
    }
#undef STAGE

    // epilogue; D layout: col = lane&15, row = (lane>>4)*4 + reg
    const int rgrp = (lane >> 4) * 4;
    const bool fin = (outf != nullptr);
#pragma unroll
    for (int jj = 0; jj < 4; ++jj) {
        int n = j0 + wx * 64 + jj * 16 + lrow;
        float bn = bias[n];
#pragma unroll
        for (int i2 = 0; i2 < 4; ++i2) {
#pragma unroll
            for (int reg = 0; reg < 4; ++reg) {
                int m = m0 + wy * 64 + i2 * 16 + rgrp + reg;
                float v = acc[i2][jj][reg] + bn;
                v = (v > 0.f) ? v : expm1f(v);
                if (fin) {
                    if (m < M) outf[(size_t)m * H + n] = v;
                } else {
                    outb[(size_t)m * 512 + H + n] = f2bf(v);
                }
            }
        }
    }
}

extern "C" void kernel_launch(void* const* d_in, const int* in_sizes, int n_in,
                              void* d_out, int out_size, void* d_ws, size_t ws_size,
                              hipStream_t stream) {
    const float* x = (const float*)d_in[0];
    const int* ei = (const int*)d_in[1];
    const float* W[6] = { (const float*)d_in[2], (const float*)d_in[3],
                          (const float*)d_in[4], (const float*)d_in[5],
                          (const float*)d_in[6], (const float*)d_in[7] };
    const float* bl[3] = { (const float*)d_in[8], (const float*)d_in[9],
                           (const float*)d_in[10] };
    float* out = (float*)d_out;

    const int N = in_sizes[0] / H;      // 50000
    const int E = in_sizes[1] / 2;      // 800000
    const int* src = ei;
    const int* dst = ei + E;
    const int mtiles = (N + 127) / 128; // 391
    const int nbuckets = (N + 63) >> 6; // 782

    // workspace carve (256B aligned)
    char* p = (char*)d_ws;
    auto carve = [&](size_t bytes) {
        char* q = p;
        p += (bytes + 255) & ~(size_t)255;
        return q;
    };
    int*            cnt      = (int*)carve((size_t)N * 4);
    int*            row_ptr  = (int*)carve((size_t)(N + 1) * 4);
    int*            cursor   = (int*)carve((size_t)N * 4);
    float*          deg_inv  = (float*)carve((size_t)N * 4);
    int*            csr_src  = (int*)carve((size_t)E * 4);
    int*            blocksum = (int*)carve((size_t)NTHREADS * 4);
    int*            blockoff = (int*)carve((size_t)NTHREADS * 4);
    int*            bcursor  = (int*)carve((size_t)(nbuckets + 1) * 4);
    int2*           tmp      = (int2*)carve((size_t)E * 8);
    unsigned short* Bcat     = (unsigned short*)carve((size_t)3 * H * 512 * 2);
    unsigned short* A0       = (unsigned short*)carve((size_t)mtiles * 128 * 512 * 2);
    unsigned short* A1       = (unsigned short*)carve((size_t)mtiles * 128 * 512 * 2);

    hipMemsetAsync(cnt, 0, (size_t)N * 4, stream);

    int n4 = N * H / 4;
    cast_x_kernel<<<(n4 + NTHREADS - 1) / NTHREADS, NTHREADS, 0, stream>>>(x, A0, n4);
    cast_w_kernel<<<(3 * H * 512) / NTHREADS, NTHREADS, 0, stream>>>(
        W[0], W[1], W[2], W[3], W[4], W[5], Bcat);

    hist_kernel<<<(E + NTHREADS - 1) / NTHREADS, NTHREADS, 0, stream>>>(dst, cnt, E);

    int nb = (N + NTHREADS - 1) / NTHREADS;   // 196 <= 256
    scan_partial_kernel<<<nb, NTHREADS, 0, stream>>>(cnt, row_ptr, blocksum, N);
    scan_sums_kernel<<<1, NTHREADS, 0, stream>>>(blocksum, blockoff, row_ptr, nb, N);
    scan_finish_kernel<<<nb, NTHREADS, 0, stream>>>(cnt, row_ptr, cursor, deg_inv, blockoff, N);

    bin_init_kernel<<<(nbuckets + NTHREADS - 1) / NTHREADS, NTHREADS, 0, stream>>>(
        row_ptr, bcursor, nbuckets, N);
    bin_fill_kernel<<<(E + NTHREADS - 1) / NTHREADS, NTHREADS, 0, stream>>>(
        src, dst, bcursor, tmp, E);
    csr_fill_kernel<<<nbuckets, NTHREADS, 0, stream>>>(
        tmp, row_ptr, cursor, csr_src, N);

    unsigned short* cur = A0;
    unsigned short* nxt = A1;
    for (int l = 0; l < 3; ++l) {
        agg_kernel<<<(N + 3) / 4, NTHREADS, 0, stream>>>(
            cur + H, cur, row_ptr, csr_src, deg_inv, N);
        gemm_kernel<<<dim3(mtiles, 2), NTHREADS, 0, stream>>>(
            cur, Bcat + (size_t)l * H * 512, bl[l],
            nxt, (l == 2) ? out : nullptr, N);
        unsigned short* t = cur; cur = nxt; nxt = t;
    }
}

// Round 10
// 456.164 us; speedup vs baseline: 1.4854x; 1.4854x over previous
//
#include <hip/hip_runtime.h>
#include <hip/hip_bf16.h>

#define H 256
#define NTHREADS 256
#define EPB 2048   // edges per block for bucket_count / bin_scatter (8 per thread)

// ---------- helpers ----------
static __device__ __forceinline__ float bf2f(unsigned short u) {
    return __uint_as_float(((unsigned int)u) << 16);
}
static __device__ __forceinline__ unsigned short f2bf(float f) {
    unsigned int x = __float_as_uint(f);
    unsigned int r = (x + 0x7fffu + ((x >> 16) & 1u)) >> 16;
    return (unsigned short)r;
}

typedef unsigned short us8 __attribute__((ext_vector_type(8)));
typedef __bf16 bf16x8 __attribute__((ext_vector_type(8)));
typedef float f32x4 __attribute__((ext_vector_type(4)));

// ---------- cast x (f32 -> bf16) into right half of Acat[m][512] ----------
__global__ __launch_bounds__(NTHREADS) void cast_x_kernel(
    const float* __restrict__ x, unsigned short* __restrict__ A, int n4)
{
    int i = blockIdx.x * NTHREADS + threadIdx.x;
    if (i < n4) {
        float4 v = ((const float4*)x)[i];
        ushort4 o;
        o.x = f2bf(v.x); o.y = f2bf(v.y); o.z = f2bf(v.z); o.w = f2bf(v.w);
        int m = i >> 6;          // 64 float4 per 256-col row
        int c = i & 63;
        ((ushort4*)(A + (size_t)m * 512 + H))[c] = o;
    }
}

// ---------- build Bcat[l][n][k] for all 3 layers in one launch ----------
// n in [0,256), k in [0,512): k<256 -> Wl[n][k], else Wr[n][k-256]
__global__ __launch_bounds__(NTHREADS) void cast_w_kernel(
    const float* __restrict__ Wl1, const float* __restrict__ Wr1,
    const float* __restrict__ Wl2, const float* __restrict__ Wr2,
    const float* __restrict__ Wl3, const float* __restrict__ Wr3,
    unsigned short* __restrict__ Bcat)
{
    int i = blockIdx.x * NTHREADS + threadIdx.x;   // 3*256*512 elements
    int l = i >> 17;
    int r = i & 131071;
    int n = r >> 9;
    int k = r & 511;
    const float* Wl = (l == 0) ? Wl1 : (l == 1) ? Wl2 : Wl3;
    const float* Wr = (l == 0) ? Wr1 : (l == 1) ? Wr2 : Wr3;
    float v = (k < H) ? Wl[n * H + k] : Wr[n * H + (k - H)];
    Bcat[i] = f2bf(v);
}

// ---------- pass 1: per-bucket edge counts (bucket = dst>>8, 256 nodes each) ----------
// LDS-aggregated: 800k per-edge LDS atomics, then <=196 global atomics per block
// (round-9 lesson: 800k GLOBAL atomics over 782 counters serialized -> 193us).
__global__ __launch_bounds__(NTHREADS) void bucket_count_kernel(
    const int* __restrict__ dst, int* __restrict__ bcnt, int E, int nbuckets)
{
    __shared__ int lc[NTHREADS];
    int t = threadIdx.x;
    lc[t] = 0;
    __syncthreads();
    int base = blockIdx.x * EPB;
#pragma unroll
    for (int j = 0; j < EPB / NTHREADS; ++j) {
        int i = base + j * NTHREADS + t;
        if (i < E) atomicAdd(&lc[dst[i] >> 8], 1);
    }
    __syncthreads();
    if (t < nbuckets && lc[t]) atomicAdd(&bcnt[t], lc[t]);
}

// ---------- pass 2: scan bucket counts -> bases; init bucket cursors ----------
__global__ __launch_bounds__(NTHREADS) void bucket_scan_kernel(
    const int* __restrict__ bcnt, int* __restrict__ bbase, int* __restrict__ bcursor,
    int* __restrict__ row_ptr, int nbuckets, int n_nodes, int E)
{
    __shared__ int sc[NTHREADS];
    int t = threadIdx.x;
    int v = (t < nbuckets) ? bcnt[t] : 0;
    sc[t] = v;
    __syncthreads();
#pragma unroll
    for (int d = 1; d < NTHREADS; d <<= 1) {
        int add = (t >= d) ? sc[t - d] : 0;
        __syncthreads();
        sc[t] += add;
        __syncthreads();
    }
    if (t < nbuckets) {
        int excl = sc[t] - v;
        bbase[t] = excl;
        bcursor[t] = excl;
    }
    if (t == 0) {
        bbase[nbuckets] = E;
        row_ptr[n_nodes] = E;
    }
}

// ---------- pass 3: scatter (src,dst) into bucket regions ----------
// Per-block LDS rank + one global atomicAdd per (block,bucket): each block's records
// for a bucket land CONTIGUOUSLY -> dense 8B writes, ~390-way (not 4000-way) contention.
__global__ __launch_bounds__(NTHREADS) void bin_scatter_kernel(
    const int* __restrict__ src, const int* __restrict__ dst,
    int* __restrict__ bcursor, int2* __restrict__ recs, int E)
{
    __shared__ int lcnt[NTHREADS];
    __shared__ int gbase[NTHREADS];
    int t = threadIdx.x;
    lcnt[t] = 0;
    __syncthreads();
    int base = blockIdx.x * EPB;
    int bkt[EPB / NTHREADS], lr[EPB / NTHREADS], sv[EPB / NTHREADS], dv[EPB / NTHREADS];
#pragma unroll
    for (int j = 0; j < EPB / NTHREADS; ++j) {
        int i = base + j * NTHREADS + t;
        if (i < E) {
            sv[j] = src[i];
            dv[j] = dst[i];
            bkt[j] = dv[j] >> 8;
            lr[j] = atomicAdd(&lcnt[bkt[j]], 1);
        } else {
            bkt[j] = -1;
        }
    }
    __syncthreads();
    if (lcnt[t]) gbase[t] = atomicAdd(&bcursor[t], lcnt[t]);
    __syncthreads();
#pragma unroll
    for (int j = 0; j < EPB / NTHREADS; ++j) {
        if (bkt[j] >= 0)
            recs[gbase[bkt[j]] + lr[j]] = make_int2(sv[j], dv[j]);
    }
}

// ---------- pass 4: per-bucket CSR build, all in LDS (replaces hist+scan+fill) ----------
// One block per bucket (256 nodes): LDS degree hist -> LDS scan -> row_ptr/deg_inv,
// then LDS-cursor scatter of csr_src into the bucket's own ~16KB window. Zero global atomics.
__global__ __launch_bounds__(NTHREADS) void csr_build_kernel(
    const int2* __restrict__ recs, const int* __restrict__ bbase,
    int* __restrict__ row_ptr, float* __restrict__ deg_inv,
    int* __restrict__ csr_src, int n_nodes)
{
    __shared__ int deg[NTHREADS];
    __shared__ int loff[NTHREADS];
    __shared__ int lcur[NTHREADS];
    int b = blockIdx.x;
    int t = threadIdx.x;
    int nlo = b << 8;
    int lo = bbase[b];
    int hi = bbase[b + 1];
    deg[t] = 0;
    __syncthreads();
    for (int i = lo + t; i < hi; i += NTHREADS)
        atomicAdd(&deg[recs[i].y & 255], 1);
    __syncthreads();
    int v = deg[t];
    loff[t] = v;
    __syncthreads();
#pragma unroll
    for (int d = 1; d < NTHREADS; d <<= 1) {
        int add = (t >= d) ? loff[t - d] : 0;
        __syncthreads();
        loff[t] += add;
        __syncthreads();
    }
    int excl = loff[t] - v;
    lcur[t] = excl;
    int node = nlo + t;
    if (node < n_nodes) {
        row_ptr[node] = lo + excl;
        deg_inv[node] = 1.0f / (float)max(v, 1);
    }
    __syncthreads();
    for (int i = lo + t; i < hi; i += NTHREADS) {
        int2 e = recs[i];
        int p = atomicAdd(&lcur[e.y & 255], 1);
        csr_src[lo + p] = e.x;
    }
}

// ---------- mean-aggregate: gather h rows (right half of Acat) -> agg (left half) ----------
// One wave per node. Lanes 0-31 even edges, 32-63 odd edges; 8 feats (16B) per lane.
__global__ __launch_bounds__(NTHREADS) void agg_kernel(
    const unsigned short* __restrict__ hsrc,   // Acat + 256 (h base), row stride 512
    unsigned short* __restrict__ aggdst,       // Acat (agg base), row stride 512
    const int* __restrict__ row_ptr, const int* __restrict__ csr_src,
    const float* __restrict__ deg_inv, int n_nodes)
{
    int wave = threadIdx.x >> 6;
    int lane = threadIdx.x & 63;
    int node = blockIdx.x * 4 + wave;
    if (node >= n_nodes) return;
    int beg = row_ptr[node];
    int cnt = row_ptr[node + 1] - beg;
    const int half = lane >> 5;
    const int foff = (lane & 31) * 8;
    const unsigned short* hb = hsrc + foff;

    float a[8] = {0.f, 0.f, 0.f, 0.f, 0.f, 0.f, 0.f, 0.f};

    for (int e = 0; e < cnt; e += 64) {
        int rem = min(64, cnt - e);
        int idx = (lane < rem) ? csr_src[beg + e + lane] : 0;
        int j = 0;
        for (; j + 16 <= rem; j += 16) {
            int s0 = __shfl(idx, j + 0 + half);
            int s1 = __shfl(idx, j + 2 + half);
            int s2 = __shfl(idx, j + 4 + half);
            int s3 = __shfl(idx, j + 6 + half);
            int s4 = __shfl(idx, j + 8 + half);
            int s5 = __shfl(idx, j + 10 + half);
            int s6 = __shfl(idx, j + 12 + half);
            int s7 = __shfl(idx, j + 14 + half);
            us8 v0 = *(const us8*)(hb + ((size_t)s0 << 9));
            us8 v1 = *(const us8*)(hb + ((size_t)s1 << 9));
            us8 v2 = *(const us8*)(hb + ((size_t)s2 << 9));
            us8 v3 = *(const us8*)(hb + ((size_t)s3 << 9));
            us8 v4 = *(const us8*)(hb + ((size_t)s4 << 9));
            us8 v5 = *(const us8*)(hb + ((size_t)s5 << 9));
            us8 v6 = *(const us8*)(hb + ((size_t)s6 << 9));
            us8 v7 = *(const us8*)(hb + ((size_t)s7 << 9));
#pragma unroll
            for (int t = 0; t < 8; ++t) a[t] += bf2f(v0[t]);
#pragma unroll
            for (int t = 0; t < 8; ++t) a[t] += bf2f(v1[t]);
#pragma unroll
            for (int t = 0; t < 8; ++t) a[t] += bf2f(v2[t]);
#pragma unroll
            for (int t = 0; t < 8; ++t) a[t] += bf2f(v3[t]);
#pragma unroll
            for (int t = 0; t < 8; ++t) a[t] += bf2f(v4[t]);
#pragma unroll
            for (int t = 0; t < 8; ++t) a[t] += bf2f(v5[t]);
#pragma unroll
            for (int t = 0; t < 8; ++t) a[t] += bf2f(v6[t]);
#pragma unroll
            for (int t = 0; t < 8; ++t) a[t] += bf2f(v7[t]);
        }
        for (; j + 8 <= rem; j += 8) {
            int s0 = __shfl(idx, j + 0 + half);
            int s1 = __shfl(idx, j + 2 + half);
            int s2 = __shfl(idx, j + 4 + half);
            int s3 = __shfl(idx, j + 6 + half);
            us8 v0 = *(const us8*)(hb + ((size_t)s0 << 9));
            us8 v1 = *(const us8*)(hb + ((size_t)s1 << 9));
            us8 v2 = *(const us8*)(hb + ((size_t)s2 << 9));
            us8 v3 = *(const us8*)(hb + ((size_t)s3 << 9));
#pragma unroll
            for (int t = 0; t < 8; ++t) a[t] += bf2f(v0[t]);
#pragma unroll
            for (int t = 0; t < 8; ++t) a[t] += bf2f(v1[t]);
#pragma unroll
            for (int t = 0; t < 8; ++t) a[t] += bf2f(v2[t]);
#pragma unroll
            for (int t = 0; t < 8; ++t) a[t] += bf2f(v3[t]);
        }
        for (; j < rem; j += 2) {
            int jj = j + half;
            int s = __shfl(idx, (jj < rem) ? jj : j);
            if (jj < rem) {
                us8 v = *(const us8*)(hb + ((size_t)s << 9));
#pragma unroll
                for (int t = 0; t < 8; ++t) a[t] += bf2f(v[t]);
            }
        }
    }

#pragma unroll
    for (int t = 0; t < 8; ++t) a[t] += __shfl_xor(a[t], 32);

    if (half == 0) {
        float di = deg_inv[node];
        us8 o;
#pragma unroll
        for (int t = 0; t < 8; ++t) o[t] = f2bf(a[t] * di);
        *(us8*)(aggdst + (size_t)node * 512 + foff) = o;
    }
}

// ---------- fused GEMM: out = ELU( Acat(M x 512) @ Bcat^T (256 x 512) + bias ) ----------
// Triple-buffered LDS (BK=32, 3x16KB=48KB -> 3 blocks/CU), COUNTED vmcnt + raw s_barrier:
// prefetch loads for tile t+1/t+2 stay in flight across the barrier. (Round-8 win: this
// broke the invariant ~61us __syncthreads-drain stall; gemm left top-5.)
__global__ __launch_bounds__(NTHREADS, 3) void gemm_kernel(
    const unsigned short* __restrict__ Acat, const unsigned short* __restrict__ Bcat,
    const float* __restrict__ bias,
    unsigned short* __restrict__ outb, float* __restrict__ outf, int M)
{
    __shared__ __align__(16) unsigned short As[3][4096];   // [buf][128 rows x 32 cols]
    __shared__ __align__(16) unsigned short Bs[3][4096];
    const int tid = threadIdx.x;
    const int lane = tid & 63;
    const int wave = tid >> 6;
    const int m0 = blockIdx.x * 128;
    const int j0 = blockIdx.y * 128;      // 2 n-tiles over N=256

    const int wy = wave >> 1;
    const int wx = wave & 1;
    const int lrow = lane & 15;
    const int kc = lane >> 4;             // 0..3 -> 16B chunk within 32-col tile row

    const int s0 = wave * 64 + lane;
    const int s1 = 256 + s0;
    const int rA0 = s0 >> 2, cA0 = (s0 & 3) ^ ((s0 >> 3) & 3);
    const int rA1 = s1 >> 2, cA1 = (s1 & 3) ^ ((s1 >> 3) & 3);
    const unsigned short* gA0 = Acat + (size_t)(m0 + rA0) * 512 + cA0 * 8;
    const unsigned short* gA1 = Acat + (size_t)(m0 + rA1) * 512 + cA1 * 8;
    const unsigned short* gB0 = Bcat + (size_t)(j0 + rA0) * 512 + cA0 * 8;
    const unsigned short* gB1 = Bcat + (size_t)(j0 + rA1) * 512 + cA1 * 8;
    const int ldsoff0 = (wave * 64) * 8;
    const int ldsoff1 = (256 + wave * 64) * 8;

    int offA[4], offB[4];
#pragma unroll
    for (int i = 0; i < 4; ++i) {
        int ra = wy * 64 + i * 16 + lrow;
        offA[i] = ra * 32 + ((kc ^ ((ra >> 1) & 3)) << 3);
        int rb = wx * 64 + i * 16 + lrow;
        offB[i] = rb * 32 + ((kc ^ ((rb >> 1) & 3)) << 3);
    }

#define STAGE(tt, buf) do {                                                         \
    const int k0_ = (tt) * 32;                                                      \
    __builtin_amdgcn_global_load_lds(                                               \
        (const __attribute__((address_space(1))) void*)(gA0 + k0_),                 \
        (__attribute__((address_space(3))) void*)(&As[buf][ldsoff0]), 16, 0, 0);    \
    __builtin_amdgcn_global_load_lds(                                               \
        (const __attribute__((address_space(1))) void*)(gA1 + k0_),                 \
        (__attribute__((address_space(3))) void*)(&As[buf][ldsoff1]), 16, 0, 0);    \
    __builtin_amdgcn_global_load_lds(                                               \
        (const __attribute__((address_space(1))) void*)(gB0 + k0_),                 \
        (__attribute__((address_space(3))) void*)(&Bs[buf][ldsoff0]), 16, 0, 0);    \
    __builtin_amdgcn_global_load_lds(                                               \
        (const __attribute__((address_space(1))) void*)(gB1 + k0_),                 \
        (__attribute__((address_space(3))) void*)(&Bs[buf][ldsoff1]), 16, 0, 0);    \
} while (0)

    f32x4 acc[4][4] = {};
    STAGE(0, 0);
    STAGE(1, 1);

    int cur = 0, stg = 2;
    for (int t = 0; t < 16; ++t) {
        if (t < 15) asm volatile("s_waitcnt vmcnt(4)" ::: "memory");
        else        asm volatile("s_waitcnt vmcnt(0)" ::: "memory");
        __builtin_amdgcn_s_barrier();
        const unsigned short* as = As[cur];
        const unsigned short* bs = Bs[cur];
        bf16x8 a[4], b[4];
#pragma unroll
        for (int i = 0; i < 4; ++i) a[i] = *(const bf16x8*)(as + offA[i]);
#pragma unroll
        for (int i = 0; i < 4; ++i) b[i] = *(const bf16x8*)(bs + offB[i]);
        if (t + 2 < 16) STAGE(t + 2, stg);
        __builtin_amdgcn_sched_barrier(0);
        __builtin_amdgcn_s_setprio(1);
#pragma unroll
        for (int i = 0; i < 4; ++i)
#pragma unroll
            for (int j = 0; j < 4; ++j)
                acc[i][j] = __builtin_amdgcn_mfma_f32_16x16x32_bf16(
                    a[i], b[j], acc[i][j], 0, 0, 0);
        __builtin_amdgcn_s_setprio(0);
        cur = (cur == 2) ? 0 : cur + 1;
        stg = (stg == 2) ? 0 : stg + 1;
    }
#undef STAGE

    // epilogue; D layout: col = lane&15, row = (lane>>4)*4 + reg
    const int rgrp = (lane >> 4) * 4;
    const bool fin = (outf != nullptr);
#pragma unroll
    for (int jj = 0; jj < 4; ++jj) {
        int n = j0 + wx * 64 + jj * 16 + lrow;
        float bn = bias[n];
#pragma unroll
        for (int i2 = 0; i2 < 4; ++i2) {
#pragma unroll
            for (int reg = 0; reg < 4; ++reg) {
                int m = m0 + wy * 64 + i2 * 16 + rgrp + reg;
                float v = acc[i2][jj][reg] + bn;
                v = (v > 0.f) ? v : expm1f(v);
                if (fin) {
                    if (m < M) outf[(size_t)m * H + n] = v;
                } else {
                    outb[(size_t)m * 512 + H + n] = f2bf(v);
                }
            }
        }
    }
}

extern "C" void kernel_launch(void* const* d_in, const int* in_sizes, int n_in,
                              void* d_out, int out_size, void* d_ws, size_t ws_size,
                              hipStream_t stream) {
    const float* x = (const float*)d_in[0];
    const int* ei = (const int*)d_in[1];
    const float* W[6] = { (const float*)d_in[2], (const float*)d_in[3],
                          (const float*)d_in[4], (const float*)d_in[5],
                          (const float*)d_in[6], (const float*)d_in[7] };
    const float* bl[3] = { (const float*)d_in[8], (const float*)d_in[9],
                           (const float*)d_in[10] };
    float* out = (float*)d_out;

    const int N = in_sizes[0] / H;      // 50000
    const int E = in_sizes[1] / 2;      // 800000
    const int* src = ei;
    const int* dst = ei + E;
    const int mtiles = (N + 127) / 128; // 391
    const int nbuckets = (N + 255) >> 8; // 196
    const int eblk = (E + EPB - 1) / EPB; // 391

    // workspace carve (256B aligned)
    char* p = (char*)d_ws;
    auto carve = [&](size_t bytes) {
        char* q = p;
        p += (bytes + 255) & ~(size_t)255;
        return q;
    };
    int*            row_ptr  = (int*)carve((size_t)(N + 1) * 4);
    float*          deg_inv  = (float*)carve((size_t)N * 4);
    int*            csr_src  = (int*)carve((size_t)E * 4);
    int*            bcnt     = (int*)carve((size_t)NTHREADS * 4);
    int*            bbase    = (int*)carve((size_t)(NTHREADS + 1) * 4);
    int*            bcursor  = (int*)carve((size_t)NTHREADS * 4);
    int2*           recs     = (int2*)carve((size_t)E * 8);
    unsigned short* Bcat     = (unsigned short*)carve((size_t)3 * H * 512 * 2);
    unsigned short* A0       = (unsigned short*)carve((size_t)mtiles * 128 * 512 * 2);
    unsigned short* A1       = (unsigned short*)carve((size_t)mtiles * 128 * 512 * 2);

    hipMemsetAsync(bcnt, 0, (size_t)NTHREADS * 4, stream);

    int n4 = N * H / 4;
    cast_x_kernel<<<(n4 + NTHREADS - 1) / NTHREADS, NTHREADS, 0, stream>>>(x, A0, n4);
    cast_w_kernel<<<(3 * H * 512) / NTHREADS, NTHREADS, 0, stream>>>(
        W[0], W[1], W[2], W[3], W[4], W[5], Bcat);

    bucket_count_kernel<<<eblk, NTHREADS, 0, stream>>>(dst, bcnt, E, nbuckets);
    bucket_scan_kernel<<<1, NTHREADS, 0, stream>>>(
        bcnt, bbase, bcursor, row_ptr, nbuckets, N, E);
    bin_scatter_kernel<<<eblk, NTHREADS, 0, stream>>>(src, dst, bcursor, recs, E);
    csr_build_kernel<<<nbuckets, NTHREADS, 0, stream>>>(
        recs, bbase, row_ptr, deg_inv, csr_src, N);

    unsigned short* cur = A0;
    unsigned short* nxt = A1;
    for (int l = 0; l < 3; ++l) {
        agg_kernel<<<(N + 3) / 4, NTHREADS, 0, stream>>>(
            cur + H, cur, row_ptr, csr_src, deg_inv, N);
        gemm_kernel<<<dim3(mtiles, 2), NTHREADS, 0, stream>>>(
            cur, Bcat + (size_t)l * H * 512, bl[l],
            nxt, (l == 2) ? out : nullptr, N);
        unsigned short* t = cur; cur = nxt; nxt = t;
    }
}